// Round 14
// baseline (265.399 us; speedup 1.0000x reference)
//
#include <hip/hip_runtime.h>
#include <hip/hip_bf16.h>

#define CEIL(a, b) (((a) + (b) - 1) / (b))

typedef __hip_bfloat16 bf16;
typedef __attribute__((ext_vector_type(4))) short s16x4;
typedef __attribute__((ext_vector_type(8))) short s16x8;
typedef __attribute__((ext_vector_type(4))) float f32x4;

// ---------------------------------------------------------------------------
// Corr_upsample_resize_norm: 6-level correlation pyramid.
// INPUT ORDER: x0, xp0, x1, xp1, ..., x5, xp5, motion_state (f32).
// OUTPUT: float32, out_size = 10,948,122: [dw0, corr0, dw1, corr1, ...].
// Level 0 is MFMA (k_corr0m): per (b, y, xhalf) block, D[x][hx] =
// sum_c f1[c,y,x]*f2[c,y+dy-4,hx] via 16x16x32 bf16 MFMA, LDS-staged.
// Scratch: dw0 region holds lc1@0, lc2@115200, lc3@125568, lc4@128160,
//   lc5@128808, P2@200000, P3@300000, P4@330000, P5@340000,
//   maxbuf[6*5832]@400000, uint slots[6]@1492986.
//   part1[3686400] @ 3359232 (corr1 region; consumed by k_red_all first).
// Order: corr0m -> lc1p -> lcrow_all -> red_all -> expand_all -> finmax ->
//        norm_all -> tail.
// ---------------------------------------------------------------------------

// Level 0 via MFMA. grid (2 xhalf, 96 y, 2 b), block 192 (3 waves = 3 m-tiles
// of 16 x). LDS: f1 row [48 x][36 cpad] bf16 + f2 rows [9 r][64 hxo][36 cpad]
// bf16 (hx = x0b + hxo - 8, OOB rows/cols zeroed -> D=0 matches zero-pad).
// Fragment (16x16x32 bf16): lane l holds m/n = l&15, k-base = (l>>4)*4;
// A/B use the IDENTICAL e->k mapping so any k permutation cancels in the dot.
// C/D (m89-verified): col(n) = l&15, row(m) = (l>>4)*4 + reg.
__global__ __launch_bounds__(192) void k_corr0m(
    const float* __restrict__ f1, const float* __restrict__ f2,
    float* __restrict__ corr0, float* __restrict__ maxbuf) {
  __shared__ bf16 lsA[48 * 36];       //  3456 bf16 =  6912 B
  __shared__ bf16 lsB[9 * 64 * 36];   // 20736 bf16 = 41472 B
  __shared__ float wm[3];

  const int tid = threadIdx.x;
  const int w = tid >> 6;   // wave = m-tile 0..2
  const int l = tid & 63;
  const int xh = blockIdx.x;
  const int y = blockIdx.y;
  const int b = blockIdx.z;
  const int x0b = xh * 48;

  const float* f1b = f1 + (size_t)b * 512 * 9216 + y * 96;
  const float* f2b = f2 + (size_t)b * 512 * 9216;

  f32x4 acc[9][2];
#pragma unroll
  for (int r = 0; r < 9; ++r)
#pragma unroll
    for (int nt = 0; nt < 2; ++nt) acc[r][nt] = (f32x4){0.f, 0.f, 0.f, 0.f};

  const int m_ = l & 15;
  const int kb = (l >> 4) * 4;
  const int aIdx = (w * 16 + m_) * 36 + kb;  // short index, 8B-aligned

  for (int ch = 0; ch < 16; ++ch) {
    const int c0 = ch * 32;
    __syncthreads();  // previous compute done before restaging

    // Stage A: 12 x-quads x 32 c (space padded to 16x32=512), vec4 loads.
#pragma unroll
    for (int i = 0; i < 3; ++i) {
      int flat = i * 192 + tid;
      int xq = flat & 15, c = flat >> 4;
      if (flat < 512 && xq < 12) {
        f32x4 v = *reinterpret_cast<const f32x4*>(
            &f1b[(size_t)(c0 + c) * 9216 + x0b + xq * 4]);
#pragma unroll
        for (int e = 0; e < 4; ++e)
          lsA[(xq * 4 + e) * 36 + c] = __float2bfloat16(v[e]);
      }
    }
    // Stage B: 9 r x 32 c x 16 hx-quads = 4608 slots / 192 thr = 24 iters.
    // Edge quads are fully in- or out-of-range (x0b, 8, 96 all mult of 4).
#pragma unroll 4
    for (int i = 0; i < 24; ++i) {
      int flat = i * 192 + tid;
      int q = flat & 15;
      int c = (flat >> 4) & 31;
      int r = flat >> 9;
      int hx0 = x0b + q * 4 - 8;
      int yy = y + r - 4;
      bool ok = (yy >= 0) && (yy < 96) && (hx0 >= 0) && (hx0 + 3 < 96);
      f32x4 v = (f32x4){0.f, 0.f, 0.f, 0.f};
      if (ok)
        v = *reinterpret_cast<const f32x4*>(
            &f2b[(size_t)(c0 + c) * 9216 + yy * 96 + hx0]);
      int base = (r * 64 + q * 4) * 36 + c;
#pragma unroll
      for (int e = 0; e < 4; ++e)
        lsB[base + e * 36] = __float2bfloat16(v[e]);
    }
    __syncthreads();

    // Compute: A frag once, 18 B frags, 18 MFMA.
    const short* lsAs = (const short*)lsA;
    const short* lsBs = (const short*)lsB;
    s16x4 a0 = *(const s16x4*)(lsAs + aIdx);
    s16x4 a1 = *(const s16x4*)(lsAs + aIdx + 16);
    s16x8 af = __builtin_shufflevector(a0, a1, 0, 1, 2, 3, 4, 5, 6, 7);
#pragma unroll
    for (int r = 0; r < 9; ++r)
#pragma unroll
      for (int nt = 0; nt < 2; ++nt) {
        int bIdx = (r * 64 + w * 16 + nt * 16 + m_) * 36 + kb;
        s16x4 b0 = *(const s16x4*)(lsBs + bIdx);
        s16x4 b1 = *(const s16x4*)(lsBs + bIdx + 16);
        s16x8 bfr = __builtin_shufflevector(b0, b1, 0, 1, 2, 3, 4, 5, 6, 7);
        acc[r][nt] = __builtin_amdgcn_mfma_f32_16x16x32_bf16(af, bfr,
                                                             acc[r][nt], 0, 0, 0);
      }
  }

  // Epilogue: tiles -> LDS [d=81][xl=48] f32 (reuse lsB: 15552 B <= 41472).
  __syncthreads();
  float* lsOut = (float*)lsB;
#pragma unroll
  for (int r = 0; r < 9; ++r)
#pragma unroll
    for (int nt = 0; nt < 2; ++nt)
#pragma unroll
      for (int reg = 0; reg < 4; ++reg) {
        int xl = w * 16 + (l >> 4) * 4 + reg;          // row (m)
        int hxl = w * 16 + nt * 16 + (l & 15) - 8;     // col (n), hx - x0b
        int dx = hxl - xl + 4;
        if (dx >= 0 && dx < 9)
          lsOut[(r * 9 + dx) * 48 + xl] = acc[r][nt][reg];
      }
  __syncthreads();

  // Coalesced store + leaky + block max. Space padded 81 x 64 = 5184 = 27*192.
  float mx = 0.f;
  for (int i = 0; i < 27; ++i) {
    int flat = i * 192 + tid;
    int xl = flat & 63, d = flat >> 6;
    if (xl < 48) {
      float v = lsOut[d * 48 + xl];
      v = v >= 0.f ? v : 0.01f * v;
      mx = fmaxf(mx, v);
      corr0[(size_t)(b * 81 + d) * 9216 + y * 96 + x0b + xl] = v;
    }
  }
#pragma unroll
  for (int off = 32; off; off >>= 1) mx = fmaxf(mx, __shfl_down(mx, off));
  if (l == 0) wm[w] = mx;
  __syncthreads();
  if (tid == 0) {
    int bid = (b * 96 + y) * 2 + xh;  // 0..383
    maxbuf[bid] = fmaxf(fmaxf(wm[0], wm[1]), wm[2]);
  }
}

// Level 1 partials, channel-split G=32. grid (48, 32, 2), block 64.
__global__ __launch_bounds__(64) void k_lc1p(
    const float* __restrict__ f1, const float* __restrict__ f2,
    float* __restrict__ part) {
  const int X = threadIdx.x;          // active < 48
  const int Y = blockIdx.x;           // 0..47
  const int gc = blockIdx.y;          // 0..31
  const int b = blockIdx.z;
  const bool xin = (X < 48);

  float acc2[5][5];
#pragma unroll
  for (int i = 0; i < 5; ++i)
#pragma unroll
    for (int j = 0; j < 5; ++j) acc2[i][j] = 0.f;

  bool okdy[5];
#pragma unroll
  for (int dy = 0; dy < 5; ++dy) {
    int YY = Y + dy - 2;
    okdy[dy] = (YY >= 0 && YY < 48);
  }
  const float* p1 = f1 + (size_t)b * 1024 * 2304 + Y * 48;
  const float* p2 = f2 + (size_t)b * 1024 * 2304;

  const int c0 = gc * 32;
#pragma unroll 2
  for (int c = c0; c < c0 + 32; ++c) {
    float a = xin ? p1[(size_t)c * 2304 + X] : 0.f;
    float as[5];
#pragma unroll
    for (int dx = 0; dx < 5; ++dx) {
      int src = X - dx + 2;
      src = src < 0 ? 0 : (src > 63 ? 63 : src);
      as[dx] = (dx == 2) ? a : __shfl(a, src);
    }
#pragma unroll
    for (int dy = 0; dy < 5; ++dy) {
      int YY = Y + dy - 2;
      float v = (okdy[dy] && xin) ? p2[(size_t)c * 2304 + YY * 48 + X] : 0.f;
#pragma unroll
      for (int dx = 0; dx < 5; ++dx)
        acc2[dy][dx] = fmaf(as[dx], v, acc2[dy][dx]);
    }
  }

  float* pb = part + ((size_t)(gc * 2 + b) * 25) * 2304 + Y * 48;
#pragma unroll
  for (int dy = 0; dy < 5; ++dy)
#pragma unroll
    for (int dx = 0; dx < 5; ++dx) {
      int src = X + dx - 2;
      int scl = src < 0 ? 0 : (src > 63 ? 63 : src);
      float val = __shfl(acc2[dy][dx], scl);
      bool okx = (X + dx - 2 >= 0) && (X + dx - 2 < 48);
      if (xin)
        pb[(size_t)(dy * 5 + dx) * 2304 + X] = (okdy[dy] && okx) ? val : 0.f;
    }
}

// Levels 2..5 partials fused. grid (17, 8, 2), block 64.
__global__ __launch_bounds__(64) void k_lcrow_all(
    const float* __restrict__ x2, const float* __restrict__ q2,
    const float* __restrict__ x3, const float* __restrict__ q3,
    const float* __restrict__ x4, const float* __restrict__ q4,
    const float* __restrict__ x5, const float* __restrict__ q5,
    float* __restrict__ out) {
  int bx = blockIdx.x;
  int S, C, RW;
  const float *f1, *f2;
  float* part;
  if (bx < 12) {
    S = 24; C = 512; RW = 2; f1 = x2; f2 = q2; part = out + 200000;
  } else if (bx < 15) {
    bx -= 12; S = 12; C = 256; RW = 5; f1 = x3; f2 = q3; part = out + 300000;
  } else if (bx < 16) {
    bx -= 15; S = 6; C = 256; RW = 10; f1 = x4; f2 = q4; part = out + 330000;
  } else {
    bx -= 16; S = 3; C = 256; RW = 21; f1 = x5; f2 = q5; part = out + 340000;
  }
  const int cpg = C / 8;
  const int lane = threadIdx.x;
  const int SS = S * S;
  const int yr = lane / S;
  const int X = lane % S;
  const int y = bx * RW + yr;
  const int gc = blockIdx.y;
  const int b = blockIdx.z;
  const bool act = (yr < RW) && (y < S);

  float acc[3][3];
#pragma unroll
  for (int i = 0; i < 3; ++i)
#pragma unroll
    for (int j = 0; j < 3; ++j) acc[i][j] = 0.f;

  bool okdx[3], okdy[3];
  int off1[3], off2[3];
#pragma unroll
  for (int i = 0; i < 3; ++i) {
    int xs = X + 1 - i;
    okdx[i] = act && (xs >= 0) && (xs < S);
    off1[i] = (act ? y : 0) * S + (xs < 0 ? 0 : (xs >= S ? S - 1 : xs));
    int yy = y + i - 1;
    okdy[i] = act && (yy >= 0) && (yy < S);
    off2[i] = (yy < 0 ? 0 : (yy >= S ? S - 1 : yy)) * S + X;
  }

  const float* f1b = f1 + (size_t)b * C * SS;
  const float* f2b = f2 + (size_t)b * C * SS;
  const int c0 = gc * cpg;
  for (int c = c0; c < c0 + cpg; ++c) {
    const float* p = f1b + (size_t)c * SS;
    const float* q = f2b + (size_t)c * SS;
    float as[3], v[3];
#pragma unroll
    for (int i = 0; i < 3; ++i) as[i] = okdx[i] ? p[off1[i]] : 0.f;
#pragma unroll
    for (int i = 0; i < 3; ++i) v[i] = okdy[i] ? q[off2[i]] : 0.f;
#pragma unroll
    for (int dy = 0; dy < 3; ++dy)
#pragma unroll
      for (int dxi = 0; dxi < 3; ++dxi)
        acc[dy][dxi] = fmaf(as[dxi], v[dy], acc[dy][dxi]);
  }

  if (act) {
    size_t base = ((size_t)(gc * 2 + b) * S + y) * 9 * S + X;
#pragma unroll
    for (int dy = 0; dy < 3; ++dy)
#pragma unroll
      for (int dxi = 0; dxi < 3; ++dxi)
        part[base + (size_t)(dy * 3 + dxi) * S] = acc[dy][dxi];
  }
}

// Fused reducer: level-1 (32 groups -> lc1) + levels 2..5 (8 groups -> lc).
__global__ __launch_bounds__(256) void k_red_all(float* __restrict__ out) {
  int t = blockIdx.x * 256 + threadIdx.x;
  if (t < 115200) {
    const float* part = out + 3359232;
    const int o = t / 4608;
    const int pix = t % 4608;
    const int b = pix / 2304, r = pix % 2304;
    float s = 0.f;
#pragma unroll
    for (int g = 0; g < 32; ++g)
      s += part[((size_t)(g * 2 + b) * 25 + o) * 2304 + r];
    out[(size_t)pix * 25 + o] = s;  // lc1 @ 0
    return;
  }
  t -= 115200;
  int S;
  const float* part;
  float* lc;
  if (t < 10368) {
    S = 24; part = out + 200000; lc = out + 115200;
  } else if ((t -= 10368) < 2592) {
    S = 12; part = out + 300000; lc = out + 125568;
  } else if ((t -= 2592) < 648) {
    S = 6; part = out + 330000; lc = out + 128160;
  } else if ((t -= 648) < 162) {
    S = 3; part = out + 340000; lc = out + 128808;
  } else {
    return;
  }
  const int SS = S * S;
  const int o = t % 9;
  const int p = t / 9;
  const int b = p / SS, r = p % SS, y = r / S, X = r % S;
  const int dy = o / 3, dx = o % 3;
  const int xs = X + dx - 1;
  float v = 0.f;
  if (xs >= 0 && xs < S) {
    size_t base = ((size_t)b * S + y) * 9 * S + (size_t)(dy * 3 + dx) * S + xs;
    const size_t gstride = (size_t)2 * S * 9 * S;
#pragma unroll
    for (int g = 0; g < 8; ++g) v += part[base + g * gstride];
  }
  lc[(size_t)p * 9 + o] = v;
}

// Expansion for levels 1..5 (fused): grid (5832, 5), blockIdx.y = lvl-1.
__global__ __launch_bounds__(256) void k_expand_all(
    float* __restrict__ out, float* __restrict__ maxbuf) {
  static const int lcoffs[6] = {0, 0, 115200, 125568, 128160, 128808};
  static const size_t dwo[6] = {0,       2985984, 4852224,
                                6438528, 7954848, 9453672};
  static const size_t cro[6] = {1492992, 3359232, 4945536,
                                6461856, 7960680, 9455130};
  const int lvl = (int)blockIdx.y + 1;
  const int R = (lvl == 1) ? 2 : 1;
  const float* lc = out + lcoffs[lvl];
  float* out_corr = out + cro[lvl];
  float* out_dw = out + dwo[lvl];
  const int t = blockIdx.x * 256 + threadIdx.x;
  float contrib = 0.f;
  {
    const int x = t % 96;
    const int y = (t / 96) % 96;
    const int d = (t / 9216) % 81;
    const int b = t / 746496;
    const int hy = y + d / 9 - 4;
    const int hx = x + d % 9 - 4;
    float val = 0.f;
    if (hy >= 0 && hy < 96 && hx >= 0 && hx < 96) {
      const int S = 96 >> lvl;
      const int Y1 = y >> lvl, X1 = x >> lvl;
      const int oy = (hy >> lvl) - Y1 + R;
      const int ox = (hx >> lvl) - X1 + R;
      const int DD = 2 * R + 1;
      val = lc[(((size_t)(b * S + Y1) * S + X1) * DD + oy) * DD + ox];
      val = val >= 0.f ? val : 0.01f * val;
    }
    out_corr[t] = val;
    const int m = (1 << lvl) - 1;
    if (((y | x) & m) == 0) {
      const int S = 96 >> lvl;
      out_dw[((size_t)(b * 81 + d) * S + (y >> lvl)) * S + (x >> lvl)] = val;
      contrib = val;
    }
  }
#pragma unroll
  for (int off = 32; off; off >>= 1)
    contrib = fmaxf(contrib, __shfl_down(contrib, off));
  __shared__ float wm[4];
  if ((threadIdx.x & 63) == 0) wm[threadIdx.x >> 6] = contrib;
  __syncthreads();
  if (threadIdx.x == 0)
    maxbuf[(size_t)lvl * 5832 + blockIdx.x] =
        fmaxf(fmaxf(wm[0], wm[1]), fmaxf(wm[2], wm[3]));
}

// Reduce per-block maxima into slots[lvl]. grid(6). Level 0 has 384 blocks.
__global__ __launch_bounds__(1024) void k_finmax(
    const float* __restrict__ maxbuf, unsigned int* __restrict__ slots) {
  const int lvl = blockIdx.x;
  const int n = (lvl == 0) ? 384 : 5832;
  const float* mb = maxbuf + (size_t)lvl * 5832;
  float m = 0.f;
  for (int i = threadIdx.x; i < n; i += 1024) m = fmaxf(m, mb[i]);
#pragma unroll
  for (int off = 32; off; off >>= 1) m = fmaxf(m, __shfl_down(m, off));
  __shared__ float wm[16];
  if ((threadIdx.x & 63) == 0) wm[threadIdx.x >> 6] = m;
  __syncthreads();
  if (threadIdx.x == 0) {
    float r = wm[0];
#pragma unroll
    for (int i = 1; i < 16; ++i) r = fmaxf(r, wm[i]);
    slots[lvl] = (unsigned int)__float_as_int(r);
  }
}

// All-level normalize (flat segmented, total 1,990,164 threads needed).
__global__ __launch_bounds__(256) void k_norm_all(
    float* __restrict__ out, const unsigned int* __restrict__ slots) {
  int i = blockIdx.x * 256 + threadIdx.x;
  int lvl;
  size_t dst, src;
  if (i < 1492986) {
    lvl = 0; dst = i; src = (size_t)1492992 + i;
  } else if ((i -= 1492986) < 373248) {
    lvl = 1; dst = (size_t)2985984 + i; src = dst;
  } else if ((i -= 373248) < 93312) {
    lvl = 2; dst = (size_t)4852224 + i; src = dst;
  } else if ((i -= 93312) < 23328) {
    lvl = 3; dst = (size_t)6438528 + i; src = dst;
  } else if ((i -= 23328) < 5832) {
    lvl = 4; dst = (size_t)7954848 + i; src = dst;
  } else if ((i -= 5832) < 1458) {
    lvl = 5; dst = (size_t)9453672 + i; src = dst;
  } else {
    return;
  }
  const float m = __int_as_float((int)slots[lvl]);
  out[dst] = out[src] / m;
}

// Last 6 dw0 elements alias the slot bytes: read slot0 first, then write.
__global__ __launch_bounds__(64) void k_norm0_tail(
    float* __restrict__ out, const unsigned int* __restrict__ slots) {
  const float m = __int_as_float((int)slots[0]);
  if (threadIdx.x < 6) {
    const int t = 1492986 + threadIdx.x;
    out[t] = out[1492992 + t] / m;
  }
}

extern "C" void kernel_launch(void* const* d_in, const int* in_sizes, int n_in,
                              void* d_out, int out_size, void* d_ws,
                              size_t ws_size, hipStream_t stream) {
  const float* x[6];
  const float* xp[6];
  for (int i = 0; i < 6; ++i) {
    x[i] = (const float*)d_in[2 * i];
    xp[i] = (const float*)d_in[2 * i + 1];
  }
  float* out = (float*)d_out;

  float* maxbuf = out + 400000;                          // 34992
  unsigned int* slots = (unsigned int*)(out + 1492986);  // 24 B
  float* part1 = out + 3359232;                          // 3686400 f32

  const int NORM_TOTAL = 1492986 + 373248 + 93312 + 23328 + 5832 + 1458;

  k_corr0m<<<dim3(2, 96, 2), dim3(192), 0, stream>>>(x[0], xp[0],
                                                     out + 1492992, maxbuf);
  k_lc1p<<<dim3(48, 32, 2), dim3(64), 0, stream>>>(x[1], xp[1], part1);
  k_lcrow_all<<<dim3(17, 8, 2), dim3(64), 0, stream>>>(
      x[2], xp[2], x[3], xp[3], x[4], xp[4], x[5], xp[5], out);
  k_red_all<<<dim3(CEIL(128970, 256)), dim3(256), 0, stream>>>(out);
  k_expand_all<<<dim3(5832, 5), dim3(256), 0, stream>>>(out, maxbuf);
  k_finmax<<<dim3(6), dim3(1024), 0, stream>>>(maxbuf, slots);
  k_norm_all<<<dim3(CEIL(NORM_TOTAL, 256)), dim3(256), 0, stream>>>(out,
                                                                    slots);
  k_norm0_tail<<<dim3(1), dim3(64), 0, stream>>>(out, slots);
}

// Round 15
// 166.528 us; speedup vs baseline: 1.5937x; 1.5937x over previous
//
#include <hip/hip_runtime.h>
#include <hip/hip_bf16.h>

#define CEIL(a, b) (((a) + (b) - 1) / (b))

typedef __hip_bfloat16 bf16;

// ---------------------------------------------------------------------------
// Corr_upsample_resize_norm: 6-level correlation pyramid.
// INPUT ORDER: x0, xp0, x1, xp1, ..., x5, xp5, motion_state (f32).
// OUTPUT: float32, out_size = 10,948,122: [dw0, corr0, dw1, corr1, ...].
// Level 0: shuffle-based VALU partials (k_corr0s) + bf16 partial reduce
// (k_corr0red). Per (xtile, y, gp=gc*3+dyg, b) wave: f1 loaded once with a
// +-4 apron, 9 shifted copies via __shfl (DS pipe), 3 straight f2 loads,
// 27 FMA per channel; 128 channels (G=4).
// Scratch: dw0 region holds lc1@0, lc2@115200, lc3@125568, lc4@128160,
//   lc5@128808, P2@200000, P3@300000, P4@330000, P5@340000,
//   maxbuf[6*5832]@400000, uint slots[6]@1492986.
//   part0: 5,971,968 bf16 @ float-elem 2985984 (consumed by k_corr0red
//     BEFORE lc1p overwrites the overlapping bytes).
//   part1[3686400] f32 @ 3359232 (consumed by k_red_all before expand_all).
// Order: corr0s -> corr0red -> lc1p -> lcrow_all -> red_all -> expand_all ->
//        finmax -> norm_all -> tail.
// ---------------------------------------------------------------------------

// Level 0 partials. grid (2 xt, 96 y, 24 = gp*2+b), block 64 (1 wave).
// gp = gc*3 + dyg; gc in [0,4) -> channels [gc*128, gc*128+128).
// Lane l: apron value a = f1[y, x0-4+l] (l<56); output x = x0+l (l<48).
// acc[j][i] on lane (x): f1[y, x+4-i] * f2[y+dyg*3+j-4, x] -- partial for
// output (x'=x+4-i, dx=i); k_corr0red regroups via xs = x'+dx-4 (as r12).
// part layout: [gp][b][y][j*9+i][x96], bf16.
__global__ __launch_bounds__(64) void k_corr0s(
    const float* __restrict__ f1, const float* __restrict__ f2,
    bf16* __restrict__ part) {
  const int l = threadIdx.x;
  const int xt = blockIdx.x;
  const int y = blockIdx.y;
  const int gp = blockIdx.z >> 1;  // 0..11
  const int b = blockIdx.z & 1;
  const int gc = gp / 3;
  const int dyg = gp % 3;
  const int x0 = xt * 48;

  float acc[3][9];
#pragma unroll
  for (int j = 0; j < 3; ++j)
#pragma unroll
    for (int i = 0; i < 9; ++i) acc[j][i] = 0.f;

  // f1 apron: lane l holds f1[y, x0-4+l] for l<56 (OOB -> 0).
  const int xa = x0 - 4 + l;
  const bool ok_a = (l < 56) && (xa >= 0) && (xa < 96);
  const int aoff = y * 96 + (xa < 0 ? 0 : (xa > 95 ? 95 : xa));
  // f2: straight loads at x = x0+l (l<48), 3 dy rows.
  const int xv = x0 + (l < 48 ? l : 47);
  bool okv[3];
  int voff[3];
#pragma unroll
  for (int j = 0; j < 3; ++j) {
    int yy = y + dyg * 3 + j - 4;
    okv[j] = (l < 48) && (yy >= 0) && (yy < 96);
    voff[j] = (yy < 0 ? 0 : (yy > 95 ? 95 : yy)) * 96 + xv;
  }

  const float* f1b = f1 + (size_t)b * 512 * 9216;
  const float* f2b = f2 + (size_t)b * 512 * 9216;
  const int c0 = gc * 128;
#pragma unroll 4
  for (int c = c0; c < c0 + 128; ++c) {
    float a = f1b[(size_t)c * 9216 + aoff];
    a = ok_a ? a : 0.f;
    float as[9];
#pragma unroll
    for (int i = 0; i < 9; ++i)
      as[i] = (i == 8) ? a : __shfl(a, l + 8 - i);
#pragma unroll
    for (int j = 0; j < 3; ++j) {
      float v = f2b[(size_t)c * 9216 + voff[j]];
      v = okv[j] ? v : 0.f;
#pragma unroll
      for (int i = 0; i < 9; ++i) acc[j][i] = fmaf(as[i], v, acc[j][i]);
    }
  }

  if (l < 48) {
    size_t base = ((size_t)(gp * 2 + b) * 96 + y) * 2592 + x0 + l;
#pragma unroll
    for (int j = 0; j < 3; ++j)
#pragma unroll
      for (int i = 0; i < 9; ++i)
        part[base + (size_t)(j * 9 + i) * 96] = __float2bfloat16(acc[j][i]);
  }
}

// Reduce 4 channel groups (bf16 partials), regroup x, leaky, store corr0,
// block max -> maxbuf. grid 5832, block 256.
__global__ __launch_bounds__(256) void k_corr0red(
    const bf16* __restrict__ part, float* __restrict__ corr0,
    float* __restrict__ maxbuf) {
  const int t = blockIdx.x * 256 + threadIdx.x;  // < 1492992 exact
  const int x = t % 96;
  const int y = (t / 96) % 96;
  const int d = (t / 9216) % 81;
  const int b = t / 746496;
  const int dy = d / 9, dx = d % 9;
  const int dyg = dy / 3, j = dy % 3;
  const int xs = x + dx - 4;
  float v = 0.f;
  if (xs >= 0 && xs < 96) {
    size_t base = ((size_t)((dyg * 2 + b) * 96 + y)) * 2592 +
                  (size_t)(j * 9 + dx) * 96 + xs;
    const size_t gstride = (size_t)6 * 96 * 2592;  // 3 dyg * 2 b * 96 * 2592
#pragma unroll
    for (int gc = 0; gc < 4; ++gc)
      v += __bfloat162float(part[base + gc * gstride]);
  }
  v = v >= 0.f ? v : 0.01f * v;
  corr0[t] = v;
  float mx = v;
#pragma unroll
  for (int off = 32; off; off >>= 1) mx = fmaxf(mx, __shfl_down(mx, off));
  __shared__ float wm[4];
  if ((threadIdx.x & 63) == 0) wm[threadIdx.x >> 6] = mx;
  __syncthreads();
  if (threadIdx.x == 0)
    maxbuf[blockIdx.x] = fmaxf(fmaxf(wm[0], wm[1]), fmaxf(wm[2], wm[3]));
}

// Level 1 partials, channel-split G=32. grid (48, 32, 2), block 64.
__global__ __launch_bounds__(64) void k_lc1p(
    const float* __restrict__ f1, const float* __restrict__ f2,
    float* __restrict__ part) {
  const int X = threadIdx.x;          // active < 48
  const int Y = blockIdx.x;           // 0..47
  const int gc = blockIdx.y;          // 0..31
  const int b = blockIdx.z;
  const bool xin = (X < 48);

  float acc2[5][5];
#pragma unroll
  for (int i = 0; i < 5; ++i)
#pragma unroll
    for (int j = 0; j < 5; ++j) acc2[i][j] = 0.f;

  bool okdy[5];
#pragma unroll
  for (int dy = 0; dy < 5; ++dy) {
    int YY = Y + dy - 2;
    okdy[dy] = (YY >= 0 && YY < 48);
  }
  const float* p1 = f1 + (size_t)b * 1024 * 2304 + Y * 48;
  const float* p2 = f2 + (size_t)b * 1024 * 2304;

  const int c0 = gc * 32;
#pragma unroll 2
  for (int c = c0; c < c0 + 32; ++c) {
    float a = xin ? p1[(size_t)c * 2304 + X] : 0.f;
    float as[5];
#pragma unroll
    for (int dx = 0; dx < 5; ++dx) {
      int src = X - dx + 2;
      src = src < 0 ? 0 : (src > 63 ? 63 : src);
      as[dx] = (dx == 2) ? a : __shfl(a, src);
    }
#pragma unroll
    for (int dy = 0; dy < 5; ++dy) {
      int YY = Y + dy - 2;
      float v = (okdy[dy] && xin) ? p2[(size_t)c * 2304 + YY * 48 + X] : 0.f;
#pragma unroll
      for (int dx = 0; dx < 5; ++dx)
        acc2[dy][dx] = fmaf(as[dx], v, acc2[dy][dx]);
    }
  }

  float* pb = part + ((size_t)(gc * 2 + b) * 25) * 2304 + Y * 48;
#pragma unroll
  for (int dy = 0; dy < 5; ++dy)
#pragma unroll
    for (int dx = 0; dx < 5; ++dx) {
      int src = X + dx - 2;
      int scl = src < 0 ? 0 : (src > 63 ? 63 : src);
      float val = __shfl(acc2[dy][dx], scl);
      bool okx = (X + dx - 2 >= 0) && (X + dx - 2 < 48);
      if (xin)
        pb[(size_t)(dy * 5 + dx) * 2304 + X] = (okdy[dy] && okx) ? val : 0.f;
    }
}

// Levels 2..5 partials fused. grid (17, 8, 2), block 64.
__global__ __launch_bounds__(64) void k_lcrow_all(
    const float* __restrict__ x2, const float* __restrict__ q2,
    const float* __restrict__ x3, const float* __restrict__ q3,
    const float* __restrict__ x4, const float* __restrict__ q4,
    const float* __restrict__ x5, const float* __restrict__ q5,
    float* __restrict__ out) {
  int bx = blockIdx.x;
  int S, C, RW;
  const float *f1, *f2;
  float* part;
  if (bx < 12) {
    S = 24; C = 512; RW = 2; f1 = x2; f2 = q2; part = out + 200000;
  } else if (bx < 15) {
    bx -= 12; S = 12; C = 256; RW = 5; f1 = x3; f2 = q3; part = out + 300000;
  } else if (bx < 16) {
    bx -= 15; S = 6; C = 256; RW = 10; f1 = x4; f2 = q4; part = out + 330000;
  } else {
    bx -= 16; S = 3; C = 256; RW = 21; f1 = x5; f2 = q5; part = out + 340000;
  }
  const int cpg = C / 8;
  const int lane = threadIdx.x;
  const int SS = S * S;
  const int yr = lane / S;
  const int X = lane % S;
  const int y = bx * RW + yr;
  const int gc = blockIdx.y;
  const int b = blockIdx.z;
  const bool act = (yr < RW) && (y < S);

  float acc[3][3];
#pragma unroll
  for (int i = 0; i < 3; ++i)
#pragma unroll
    for (int j = 0; j < 3; ++j) acc[i][j] = 0.f;

  bool okdx[3], okdy[3];
  int off1[3], off2[3];
#pragma unroll
  for (int i = 0; i < 3; ++i) {
    int xs = X + 1 - i;
    okdx[i] = act && (xs >= 0) && (xs < S);
    off1[i] = (act ? y : 0) * S + (xs < 0 ? 0 : (xs >= S ? S - 1 : xs));
    int yy = y + i - 1;
    okdy[i] = act && (yy >= 0) && (yy < S);
    off2[i] = (yy < 0 ? 0 : (yy >= S ? S - 1 : yy)) * S + X;
  }

  const float* f1b = f1 + (size_t)b * C * SS;
  const float* f2b = f2 + (size_t)b * C * SS;
  const int c0 = gc * cpg;
  for (int c = c0; c < c0 + cpg; ++c) {
    const float* p = f1b + (size_t)c * SS;
    const float* q = f2b + (size_t)c * SS;
    float as[3], v[3];
#pragma unroll
    for (int i = 0; i < 3; ++i) as[i] = okdx[i] ? p[off1[i]] : 0.f;
#pragma unroll
    for (int i = 0; i < 3; ++i) v[i] = okdy[i] ? q[off2[i]] : 0.f;
#pragma unroll
    for (int dy = 0; dy < 3; ++dy)
#pragma unroll
      for (int dxi = 0; dxi < 3; ++dxi)
        acc[dy][dxi] = fmaf(as[dxi], v[dy], acc[dy][dxi]);
  }

  if (act) {
    size_t base = ((size_t)(gc * 2 + b) * S + y) * 9 * S + X;
#pragma unroll
    for (int dy = 0; dy < 3; ++dy)
#pragma unroll
      for (int dxi = 0; dxi < 3; ++dxi)
        part[base + (size_t)(dy * 3 + dxi) * S] = acc[dy][dxi];
  }
}

// Fused reducer: level-1 (32 groups -> lc1) + levels 2..5 (8 groups -> lc).
__global__ __launch_bounds__(256) void k_red_all(float* __restrict__ out) {
  int t = blockIdx.x * 256 + threadIdx.x;
  if (t < 115200) {
    const float* part = out + 3359232;
    const int o = t / 4608;
    const int pix = t % 4608;
    const int b = pix / 2304, r = pix % 2304;
    float s = 0.f;
#pragma unroll
    for (int g = 0; g < 32; ++g)
      s += part[((size_t)(g * 2 + b) * 25 + o) * 2304 + r];
    out[(size_t)pix * 25 + o] = s;  // lc1 @ 0
    return;
  }
  t -= 115200;
  int S;
  const float* part;
  float* lc;
  if (t < 10368) {
    S = 24; part = out + 200000; lc = out + 115200;
  } else if ((t -= 10368) < 2592) {
    S = 12; part = out + 300000; lc = out + 125568;
  } else if ((t -= 2592) < 648) {
    S = 6; part = out + 330000; lc = out + 128160;
  } else if ((t -= 648) < 162) {
    S = 3; part = out + 340000; lc = out + 128808;
  } else {
    return;
  }
  const int SS = S * S;
  const int o = t % 9;
  const int p = t / 9;
  const int b = p / SS, r = p % SS, y = r / S, X = r % S;
  const int dy = o / 3, dx = o % 3;
  const int xs = X + dx - 1;
  float v = 0.f;
  if (xs >= 0 && xs < S) {
    size_t base = ((size_t)b * S + y) * 9 * S + (size_t)(dy * 3 + dx) * S + xs;
    const size_t gstride = (size_t)2 * S * 9 * S;
#pragma unroll
    for (int g = 0; g < 8; ++g) v += part[base + g * gstride];
  }
  lc[(size_t)p * 9 + o] = v;
}

// Expansion for levels 1..5 (fused): grid (5832, 5), blockIdx.y = lvl-1.
__global__ __launch_bounds__(256) void k_expand_all(
    float* __restrict__ out, float* __restrict__ maxbuf) {
  static const int lcoffs[6] = {0, 0, 115200, 125568, 128160, 128808};
  static const size_t dwo[6] = {0,       2985984, 4852224,
                                6438528, 7954848, 9453672};
  static const size_t cro[6] = {1492992, 3359232, 4945536,
                                6461856, 7960680, 9455130};
  const int lvl = (int)blockIdx.y + 1;
  const int R = (lvl == 1) ? 2 : 1;
  const float* lc = out + lcoffs[lvl];
  float* out_corr = out + cro[lvl];
  float* out_dw = out + dwo[lvl];
  const int t = blockIdx.x * 256 + threadIdx.x;
  float contrib = 0.f;
  {
    const int x = t % 96;
    const int y = (t / 96) % 96;
    const int d = (t / 9216) % 81;
    const int b = t / 746496;
    const int hy = y + d / 9 - 4;
    const int hx = x + d % 9 - 4;
    float val = 0.f;
    if (hy >= 0 && hy < 96 && hx >= 0 && hx < 96) {
      const int S = 96 >> lvl;
      const int Y1 = y >> lvl, X1 = x >> lvl;
      const int oy = (hy >> lvl) - Y1 + R;
      const int ox = (hx >> lvl) - X1 + R;
      const int DD = 2 * R + 1;
      val = lc[(((size_t)(b * S + Y1) * S + X1) * DD + oy) * DD + ox];
      val = val >= 0.f ? val : 0.01f * val;
    }
    out_corr[t] = val;
    const int m = (1 << lvl) - 1;
    if (((y | x) & m) == 0) {
      const int S = 96 >> lvl;
      out_dw[((size_t)(b * 81 + d) * S + (y >> lvl)) * S + (x >> lvl)] = val;
      contrib = val;
    }
  }
#pragma unroll
  for (int off = 32; off; off >>= 1)
    contrib = fmaxf(contrib, __shfl_down(contrib, off));
  __shared__ float wm[4];
  if ((threadIdx.x & 63) == 0) wm[threadIdx.x >> 6] = contrib;
  __syncthreads();
  if (threadIdx.x == 0)
    maxbuf[(size_t)lvl * 5832 + blockIdx.x] =
        fmaxf(fmaxf(wm[0], wm[1]), fmaxf(wm[2], wm[3]));
}

// Reduce per-block maxima (5832 per level) into slots[lvl]. grid(6).
__global__ __launch_bounds__(1024) void k_finmax(
    const float* __restrict__ maxbuf, unsigned int* __restrict__ slots) {
  const int lvl = blockIdx.x;
  const float* mb = maxbuf + (size_t)lvl * 5832;
  float m = 0.f;
  for (int i = threadIdx.x; i < 5832; i += 1024) m = fmaxf(m, mb[i]);
#pragma unroll
  for (int off = 32; off; off >>= 1) m = fmaxf(m, __shfl_down(m, off));
  __shared__ float wm[16];
  if ((threadIdx.x & 63) == 0) wm[threadIdx.x >> 6] = m;
  __syncthreads();
  if (threadIdx.x == 0) {
    float r = wm[0];
#pragma unroll
    for (int i = 1; i < 16; ++i) r = fmaxf(r, wm[i]);
    slots[lvl] = (unsigned int)__float_as_int(r);
  }
}

// All-level normalize (flat segmented, total 1,990,164 threads needed).
__global__ __launch_bounds__(256) void k_norm_all(
    float* __restrict__ out, const unsigned int* __restrict__ slots) {
  int i = blockIdx.x * 256 + threadIdx.x;
  int lvl;
  size_t dst, src;
  if (i < 1492986) {
    lvl = 0; dst = i; src = (size_t)1492992 + i;
  } else if ((i -= 1492986) < 373248) {
    lvl = 1; dst = (size_t)2985984 + i; src = dst;
  } else if ((i -= 373248) < 93312) {
    lvl = 2; dst = (size_t)4852224 + i; src = dst;
  } else if ((i -= 93312) < 23328) {
    lvl = 3; dst = (size_t)6438528 + i; src = dst;
  } else if ((i -= 23328) < 5832) {
    lvl = 4; dst = (size_t)7954848 + i; src = dst;
  } else if ((i -= 5832) < 1458) {
    lvl = 5; dst = (size_t)9453672 + i; src = dst;
  } else {
    return;
  }
  const float m = __int_as_float((int)slots[lvl]);
  out[dst] = out[src] / m;
}

// Last 6 dw0 elements alias the slot bytes: read slot0 first, then write.
__global__ __launch_bounds__(64) void k_norm0_tail(
    float* __restrict__ out, const unsigned int* __restrict__ slots) {
  const float m = __int_as_float((int)slots[0]);
  if (threadIdx.x < 6) {
    const int t = 1492986 + threadIdx.x;
    out[t] = out[1492992 + t] / m;
  }
}

extern "C" void kernel_launch(void* const* d_in, const int* in_sizes, int n_in,
                              void* d_out, int out_size, void* d_ws,
                              size_t ws_size, hipStream_t stream) {
  const float* x[6];
  const float* xp[6];
  for (int i = 0; i < 6; ++i) {
    x[i] = (const float*)d_in[2 * i];
    xp[i] = (const float*)d_in[2 * i + 1];
  }
  float* out = (float*)d_out;

  float* maxbuf = out + 400000;                          // 34992
  unsigned int* slots = (unsigned int*)(out + 1492986);  // 24 B
  bf16* part0 = (bf16*)(out + 2985984);                  // 5,971,968 bf16
  float* part1 = out + 3359232;                          // 3686400 f32

  const int NORM_TOTAL = 1492986 + 373248 + 93312 + 23328 + 5832 + 1458;

  k_corr0s<<<dim3(2, 96, 24), dim3(64), 0, stream>>>(x[0], xp[0], part0);
  k_corr0red<<<dim3(5832), dim3(256), 0, stream>>>(part0, out + 1492992,
                                                   maxbuf);
  k_lc1p<<<dim3(48, 32, 2), dim3(64), 0, stream>>>(x[1], xp[1], part1);
  k_lcrow_all<<<dim3(17, 8, 2), dim3(64), 0, stream>>>(
      x[2], xp[2], x[3], xp[3], x[4], xp[4], x[5], xp[5], out);
  k_red_all<<<dim3(CEIL(128970, 256)), dim3(256), 0, stream>>>(out);
  k_expand_all<<<dim3(5832, 5), dim3(256), 0, stream>>>(out, maxbuf);
  k_finmax<<<dim3(6), dim3(1024), 0, stream>>>(maxbuf, slots);
  k_norm_all<<<dim3(CEIL(NORM_TOTAL, 256)), dim3(256), 0, stream>>>(out,
                                                                    slots);
  k_norm0_tail<<<dim3(1), dim3(64), 0, stream>>>(out, slots);
}